// Round 1
// 1766.622 us; speedup vs baseline: 1.0172x; 1.0172x over previous
//
#include <hip/hip_runtime.h>
#include <hip/hip_bf16.h>

// ---------------------------------------------------------------------------
// VisualHead forward. Round 4:
//  - Expert-batched conv launches: k_conv1_all (grid 4096, 4 Y1 buffers),
//    k_conv2_all (grid 2048, atomicAdd accumulation into zeroed MOE).
//    Removes the 15 serialized per-expert dependency edges and lifts
//    blocks/CU from 2 to 8+ on the barrier-bound m97 structure.
//  - XCD-aware bijective block swizzle on both conv kernels.
//  - k_wt_all: single launch for all 8 conv-weight transposes.
//  - Runtime fallback to the previous verified serial path if ws_size
//    < ~280 MB (batched layout needs 4x Y1 + 4x W1T/W2T).
//  - fc1 split-bf16 MFMA, classifier MFMA, norm/gate/ln/softmax unchanged.
// ---------------------------------------------------------------------------

namespace {

constexpr int kB = 16, kT = 512, kD = 1024, kFF = 2048, kE = 4, kCLS = 1200;
constexpr int kM = kB * kT;                    // 8192
constexpr int kTP = kT + 2;                    // padded seq len
constexpr int kCLSP = 1280;                    // padded classifier rows
constexpr size_t kBTD = (size_t)kM * kD;
constexpr size_t kBTC = (size_t)kM * kCLS;
constexpr size_t kY1S = (size_t)kB * kTP * kFF;   // per-expert Y1 elems (bf16)

// ---------------- serial (fallback) workspace layout (float units) --------
constexpr size_t WS_H     = 0;                                   // fp32 [M,D]; later MOE accum
constexpr size_t WS_HPAD  = WS_H + kBTD;                         // bf16 [B*kTP, D]
constexpr size_t WS_Y1P   = WS_HPAD + (size_t)kB * kTP * kD / 2; // bf16 [B*kTP, FF]; aliased: XHI/XLO (fc1), FEATB (epilogue)
constexpr size_t WS_W1T   = WS_Y1P + (size_t)kB * kTP * kFF / 2; // bf16 [3,FF,D]
constexpr size_t WS_W2T   = WS_W1T + (size_t)3 * kFF * kD / 2;   // bf16 [3,D,FF]
constexpr size_t WS_GATES = WS_W2T + (size_t)3 * kD * kFF / 2;   // fp32 [M,4]
constexpr size_t WS_PROBS = WS_GATES + (size_t)kM * kE;          // fp32 [M,4]
constexpr size_t WS_W1HI  = WS_PROBS + (size_t)kM * kE;          // bf16 [D,D]
constexpr size_t WS_W1LO  = WS_W1HI + (size_t)kD * kD / 2;       // bf16 [D,D]
constexpr size_t WS_OWB   = WS_W1LO + (size_t)kD * kD / 2;       // bf16 [1280,D]
constexpr size_t WS_SUMS  = WS_OWB + (size_t)kCLSP * kD / 2;
constexpr size_t WS_SUMSQ = WS_SUMS + kD;
constexpr size_t WS_CNT   = WS_SUMSQ + kD;
constexpr size_t WS_AA    = WS_CNT + 1;
constexpr size_t WS_CC    = WS_AA + kD;
constexpr int WS_ZERON = (int)(2 * kD + 1);    // SUMS, SUMSQ, CNT

// ---------------- batched workspace layout (float units) -------------------
constexpr size_t BW_H     = 0;                                    // fp32 [M,D]; later MOE
constexpr size_t BW_HPAD  = BW_H + kBTD;                          // bf16 [B*kTP, D]
constexpr size_t BW_Y1    = BW_HPAD + (size_t)kB * kTP * kD / 2;  // bf16 [E][B*kTP,FF]; aliased XHI/XLO (fc1), FEATB (epi)
constexpr size_t BW_W1T   = BW_Y1 + (size_t)kE * kY1S / 2;        // bf16 [E][3][FF,D]
constexpr size_t BW_W2T   = BW_W1T + (size_t)kE * 3 * kFF * kD / 2; // bf16 [E][3][D,FF]
constexpr size_t BW_GATES = BW_W2T + (size_t)kE * 3 * kD * kFF / 2; // fp32 [M,4]
constexpr size_t BW_PROBS = BW_GATES + (size_t)kM * kE;           // fp32 [M,4]
constexpr size_t BW_W1HI  = BW_PROBS + (size_t)kM * kE;           // bf16 [D,D]
constexpr size_t BW_W1LO  = BW_W1HI + (size_t)kD * kD / 2;        // bf16 [D,D]
constexpr size_t BW_OWB   = BW_W1LO + (size_t)kD * kD / 2;        // bf16 [1280,D]
constexpr size_t BW_SUMS  = BW_OWB + (size_t)kCLSP * kD / 2;
constexpr size_t BW_SUMSQ = BW_SUMS + kD;
constexpr size_t BW_CNT   = BW_SUMSQ + kD;
constexpr size_t BW_AA    = BW_CNT + 1;
constexpr size_t BW_CC    = BW_AA + kD;
constexpr size_t BW_END   = BW_CC + kD;                           // ~73.2M floats = ~280 MB

typedef __attribute__((ext_vector_type(8))) short short8;
typedef __attribute__((ext_vector_type(4))) float f32x4;

#define GLOBAL_LOAD_LDS16(gp, lp)                                          \
  __builtin_amdgcn_global_load_lds(                                        \
      (const __attribute__((address_space(1))) void*)(gp),                 \
      (__attribute__((address_space(3))) void*)(lp), 16, 0, 0)

__device__ __forceinline__ float block_reduce_sum(float v, float* red) {
  const int tid = threadIdx.x;
  __syncthreads();
  red[tid] = v;
  __syncthreads();
  for (int s = 128; s > 0; s >>= 1) {
    if (tid < s) red[tid] += red[tid + s];
    __syncthreads();
  }
  return red[0];
}

__device__ __forceinline__ float block_reduce_max(float v, float* red) {
  const int tid = threadIdx.x;
  __syncthreads();
  red[tid] = v;
  __syncthreads();
  for (int s = 128; s > 0; s >>= 1) {
    if (tid < s) red[tid] = fmaxf(red[tid], red[tid + s]);
    __syncthreads();
  }
  return red[0];
}

__global__ void k_zero(float* __restrict__ p, int n) {
  int i = blockIdx.x * 256 + threadIdx.x;
  if (i < n) p[i] = 0.f;
}

// zero sentinel rows (t=-1, t=T) of Hpad and Y1pad (serial path)
__global__ void k_zero_bnd(__hip_bfloat16* __restrict__ Hpad,
                           __hip_bfloat16* __restrict__ Y1pad) {
  const int b = blockIdx.x >> 1;
  const int row = b * kTP + ((blockIdx.x & 1) ? (kTP - 1) : 0);
  const __hip_bfloat16 z = __float2bfloat16(0.f);
  for (int d = threadIdx.x; d < kD; d += 256) Hpad[(size_t)row * kD + d] = z;
  for (int d = threadIdx.x; d < kFF; d += 256) Y1pad[(size_t)row * kFF + d] = z;
}

// zero sentinel rows of Hpad and all 4 expert Y1 buffers (batched path)
__global__ void k_zero_bnd_all(__hip_bfloat16* __restrict__ Hpad,
                               __hip_bfloat16* __restrict__ Y1all) {
  const int g = blockIdx.x;            // [0, 2*kB*(1+kE))
  const int which = g / (2 * kB);      // 0: Hpad, 1..4: expert e = which-1
  const int r = g % (2 * kB);
  const int b = r >> 1;
  const int row = b * kTP + ((r & 1) ? (kTP - 1) : 0);
  const __hip_bfloat16 z = __float2bfloat16(0.f);
  if (which == 0) {
    for (int d = threadIdx.x; d < kD; d += 256) Hpad[(size_t)row * kD + d] = z;
  } else {
    __hip_bfloat16* Y = Y1all + (size_t)(which - 1) * kY1S;
    for (int d = threadIdx.x; d < kFF; d += 256) Y[(size_t)row * kFF + d] = z;
  }
}

// fp32 -> (hi, lo) bf16 split; 4 elems/thread
__global__ __launch_bounds__(256) void k_split(const float* __restrict__ src,
                                               __hip_bfloat16* __restrict__ hi,
                                               __hip_bfloat16* __restrict__ lo,
                                               int n4) {
  const int i = blockIdx.x * 256 + threadIdx.x;
  if (i >= n4) return;
  const float4 v = *reinterpret_cast<const float4*>(src + (size_t)i * 4);
  const float vv[4] = {v.x, v.y, v.z, v.w};
  unsigned short h[4], l[4];
#pragma unroll
  for (int j = 0; j < 4; ++j) {
    __hip_bfloat16 hb = __float2bfloat16(vv[j]);
    __hip_bfloat16 lb = __float2bfloat16(vv[j] - __bfloat162float(hb));
    h[j] = *reinterpret_cast<unsigned short*>(&hb);
    l[j] = *reinterpret_cast<unsigned short*>(&lb);
  }
  *reinterpret_cast<short4*>(hi + (size_t)i * 4) =
      make_short4(h[0], h[1], h[2], h[3]);
  *reinterpret_cast<short4*>(lo + (size_t)i * 4) =
      make_short4(l[0], l[1], l[2], l[3]);
}

// out_w [1200,D] fp32 -> OWB [1280,D] bf16, zero padded rows
__global__ __launch_bounds__(256) void k_wcast_pad(
    const float* __restrict__ w, __hip_bfloat16* __restrict__ dst) {
  const size_t i = (size_t)blockIdx.x * 256 + threadIdx.x;
  if (i >= (size_t)kCLSP * kD) return;
  const size_t r = i / kD;
  dst[i] = __float2bfloat16(r < kCLS ? w[i] : 0.f);
}

// conv weight transpose+cast (serial path): src [O][I][3] fp32 -> dst [3][O][I] bf16
__global__ __launch_bounds__(256) void k_wt(const float* __restrict__ src,
                                            __hip_bfloat16* __restrict__ dst,
                                            int n) {
  const int i = blockIdx.x * 256 + threadIdx.x;
  if (i >= n) return;
  const float* s = src + (size_t)i * 3;
  dst[i] = __float2bfloat16(s[0]);
  dst[(size_t)n + i] = __float2bfloat16(s[1]);
  dst[(size_t)2 * n + i] = __float2bfloat16(s[2]);
}

// batched weight transpose+cast for all experts, both convs
__global__ __launch_bounds__(256) void k_wt_all(const float* __restrict__ ew1,
                                                const float* __restrict__ ew2,
                                                __hip_bfloat16* __restrict__ W1T,
                                                __hip_bfloat16* __restrict__ W2T) {
  const size_t n = (size_t)kFF * kD;       // per-expert per-conv [O][I] elems
  const size_t total = (size_t)kE * n;
  const size_t i = (size_t)blockIdx.x * 256 + threadIdx.x;
  if (i >= total) return;
  const size_t e = i / n, j = i - e * n;
  {
    const float* s = ew1 + (e * n + j) * 3;
    __hip_bfloat16* d = W1T + e * 3 * n;
    d[j] = __float2bfloat16(s[0]);
    d[n + j] = __float2bfloat16(s[1]);
    d[2 * n + j] = __float2bfloat16(s[2]);
  }
  {
    const float* s = ew2 + (e * n + j) * 3;
    __hip_bfloat16* d = W2T + e * 3 * n;
    d[j] = __float2bfloat16(s[0]);
    d[n + j] = __float2bfloat16(s[1]);
    d[2 * n + j] = __float2bfloat16(s[2]);
  }
}

// ----- fc1: H = (Xhi+Xlo) @ (Whi+Wlo)^T + b, via hi*hi + lo*hi + hi*lo -----
__global__ __launch_bounds__(256) void k_fc1_mfma(
    const __hip_bfloat16* __restrict__ Xhi, const __hip_bfloat16* __restrict__ Xlo,
    const __hip_bfloat16* __restrict__ Whi, const __hip_bfloat16* __restrict__ Wlo,
    const float* __restrict__ bias, float* __restrict__ H) {
  __shared__ __align__(16) __hip_bfloat16 As[128 * 32];
  __shared__ __align__(16) __hip_bfloat16 Bs[128 * 32];
  const int tid = threadIdx.x;
  const int m0 = blockIdx.y * 128;
  const int n0 = blockIdx.x * 128;
  const int w = tid >> 6, lane = tid & 63;
  const int wm = (w >> 1) * 64, wn = (w & 1) * 64;
  f32x4 acc[4][4] = {};
  const int fr = lane & 15, fc = (lane >> 4) * 8;
  const __hip_bfloat16* Aps[3] = {Xhi, Xlo, Xhi};
  const __hip_bfloat16* Bps[3] = {Whi, Whi, Wlo};
  for (int p = 0; p < 3; ++p) {
    const __hip_bfloat16* Ab = Aps[p] + (size_t)m0 * kD;
    const __hip_bfloat16* Bb = Bps[p] + (size_t)n0 * kD;
    for (int k0 = 0; k0 < kD; k0 += 32) {
      __syncthreads();
#pragma unroll
      for (int r = 0; r < 2; ++r) {
        const int idx = r * 256 + tid;
        const int row = idx >> 2, cg = (idx & 3) * 8;
        GLOBAL_LOAD_LDS16(Ab + (size_t)row * kD + k0 + cg, &As[idx * 8]);
        GLOBAL_LOAD_LDS16(Bb + (size_t)row * kD + k0 + cg, &Bs[idx * 8]);
      }
      __syncthreads();
      short8 af[4], bf[4];
#pragma unroll
      for (int i = 0; i < 4; ++i) {
        af[i] = *reinterpret_cast<const short8*>(&As[(wm + i * 16 + fr) * 32 + fc]);
        bf[i] = *reinterpret_cast<const short8*>(&Bs[(wn + i * 16 + fr) * 32 + fc]);
      }
#pragma unroll
      for (int i = 0; i < 4; ++i)
#pragma unroll
        for (int j = 0; j < 4; ++j)
          acc[i][j] = __builtin_amdgcn_mfma_f32_16x16x32_bf16(af[i], bf[j], acc[i][j], 0, 0, 0);
    }
  }
  const int cr = (lane >> 4) * 4, cc = lane & 15;
#pragma unroll
  for (int i = 0; i < 4; ++i) {
#pragma unroll
    for (int r = 0; r < 4; ++r) {
      const int m = m0 + wm + i * 16 + cr + r;
#pragma unroll
      for (int j = 0; j < 4; ++j) {
        const int gc = n0 + wn + j * 16 + cc;
        H[(size_t)m * kD + gc] = acc[i][j][r] + bias[gc];
      }
    }
  }
}

// ----- classifier: logits = featb @ OWB^T + out_b (N padded to 1280) -----
__global__ __launch_bounds__(256) void k_cls_mfma(
    const __hip_bfloat16* __restrict__ Fb, const __hip_bfloat16* __restrict__ Wb,
    const float* __restrict__ bias, float* __restrict__ logits) {
  __shared__ __align__(16) __hip_bfloat16 As[128 * 32];
  __shared__ __align__(16) __hip_bfloat16 Bs[128 * 32];
  const int tid = threadIdx.x;
  const int m0 = blockIdx.y * 128;
  const int n0 = blockIdx.x * 128;
  const int w = tid >> 6, lane = tid & 63;
  const int wm = (w >> 1) * 64, wn = (w & 1) * 64;
  f32x4 acc[4][4] = {};
  const int fr = lane & 15, fc = (lane >> 4) * 8;
  const __hip_bfloat16* Ab = Fb + (size_t)m0 * kD;
  const __hip_bfloat16* Bb = Wb + (size_t)n0 * kD;
  for (int k0 = 0; k0 < kD; k0 += 32) {
    __syncthreads();
#pragma unroll
    for (int r = 0; r < 2; ++r) {
      const int idx = r * 256 + tid;
      const int row = idx >> 2, cg = (idx & 3) * 8;
      GLOBAL_LOAD_LDS16(Ab + (size_t)row * kD + k0 + cg, &As[idx * 8]);
      GLOBAL_LOAD_LDS16(Bb + (size_t)row * kD + k0 + cg, &Bs[idx * 8]);
    }
    __syncthreads();
    short8 af[4], bf[4];
#pragma unroll
    for (int i = 0; i < 4; ++i) {
      af[i] = *reinterpret_cast<const short8*>(&As[(wm + i * 16 + fr) * 32 + fc]);
      bf[i] = *reinterpret_cast<const short8*>(&Bs[(wn + i * 16 + fr) * 32 + fc]);
    }
#pragma unroll
    for (int i = 0; i < 4; ++i)
#pragma unroll
      for (int j = 0; j < 4; ++j)
        acc[i][j] = __builtin_amdgcn_mfma_f32_16x16x32_bf16(af[i], bf[j], acc[i][j], 0, 0, 0);
  }
  const int cr = (lane >> 4) * 4, cc = lane & 15;
#pragma unroll
  for (int i = 0; i < 4; ++i) {
#pragma unroll
    for (int r = 0; r < 4; ++r) {
      const int m = m0 + wm + i * 16 + cr + r;
#pragma unroll
      for (int j = 0; j < 4; ++j) {
        const int gc = n0 + wn + j * 16 + cc;
        if (gc < kCLS) logits[(size_t)m * kCLS + gc] = acc[i][j][r] + bias[gc];
      }
    }
  }
}

// ----- serial-path MFMA conv kernels (fallback, unchanged) -----
__global__ __launch_bounds__(256) void k_conv1_mfma(
    const __hip_bfloat16* __restrict__ Hpad, const __hip_bfloat16* __restrict__ W1T,
    const float* __restrict__ b1, __hip_bfloat16* __restrict__ Y1pad) {
  __shared__ __align__(16) __hip_bfloat16 As[128 * 32];
  __shared__ __align__(16) __hip_bfloat16 Bs[128 * 32];
  const int tid = threadIdx.x;
  const int m0 = blockIdx.y * 128;
  const int n0 = blockIdx.x * 128;
  const int b = m0 >> 9;
  const int t0 = m0 & (kT - 1);
  const int arow0 = b * kTP + t0;
  const int w = tid >> 6, lane = tid & 63;
  const int wm = (w >> 1) * 64, wn = (w & 1) * 64;
  f32x4 acc[4][4] = {};
  const int fr = lane & 15, fc = (lane >> 4) * 8;
  for (int kk = 0; kk < 3; ++kk) {
    const __hip_bfloat16* Ab = Hpad + (size_t)(arow0 + kk) * kD;
    const __hip_bfloat16* Bb = W1T + (size_t)kk * kFF * kD + (size_t)n0 * kD;
    for (int k0 = 0; k0 < kD; k0 += 32) {
      __syncthreads();
#pragma unroll
      for (int r = 0; r < 2; ++r) {
        const int idx = r * 256 + tid;
        const int row = idx >> 2, cg = (idx & 3) * 8;
        GLOBAL_LOAD_LDS16(Ab + (size_t)row * kD + k0 + cg, &As[idx * 8]);
        GLOBAL_LOAD_LDS16(Bb + (size_t)row * kD + k0 + cg, &Bs[idx * 8]);
      }
      __syncthreads();
      short8 af[4], bf[4];
#pragma unroll
      for (int i = 0; i < 4; ++i) {
        af[i] = *reinterpret_cast<const short8*>(&As[(wm + i * 16 + fr) * 32 + fc]);
        bf[i] = *reinterpret_cast<const short8*>(&Bs[(wn + i * 16 + fr) * 32 + fc]);
      }
#pragma unroll
      for (int i = 0; i < 4; ++i)
#pragma unroll
        for (int j = 0; j < 4; ++j)
          acc[i][j] = __builtin_amdgcn_mfma_f32_16x16x32_bf16(af[i], bf[j], acc[i][j], 0, 0, 0);
    }
  }
  const int orow0 = b * kTP + t0 + 1;
  const int cr = (lane >> 4) * 4, cc = lane & 15;
#pragma unroll
  for (int i = 0; i < 4; ++i) {
#pragma unroll
    for (int r = 0; r < 4; ++r) {
      const int lr = wm + i * 16 + cr + r;
#pragma unroll
      for (int j = 0; j < 4; ++j) {
        const int gc = n0 + wn + j * 16 + cc;
        const float v = acc[i][j][r] + b1[gc];
        Y1pad[(size_t)(orow0 + lr) * kFF + gc] = __float2bfloat16(fmaxf(v, 0.f));
      }
    }
  }
}

__global__ __launch_bounds__(256) void k_conv2_mfma(
    const __hip_bfloat16* __restrict__ Y1pad, const __hip_bfloat16* __restrict__ W2T,
    const float* __restrict__ b2, const float* __restrict__ gates,
    int e, float* __restrict__ moe) {
  __shared__ __align__(16) __hip_bfloat16 As[128 * 32];
  __shared__ __align__(16) __hip_bfloat16 Bs[128 * 32];
  const int tid = threadIdx.x;
  const int m0 = blockIdx.y * 128;
  const int n0 = blockIdx.x * 128;
  const int b = m0 >> 9;
  const int t0 = m0 & (kT - 1);
  const int arow0 = b * kTP + t0;
  const int w = tid >> 6, lane = tid & 63;
  const int wm = (w >> 1) * 64, wn = (w & 1) * 64;
  f32x4 acc[4][4] = {};
  const int fr = lane & 15, fc = (lane >> 4) * 8;
  for (int kk = 0; kk < 3; ++kk) {
    const __hip_bfloat16* Ab = Y1pad + (size_t)(arow0 + kk) * kFF;
    const __hip_bfloat16* Bb = W2T + (size_t)kk * kD * kFF + (size_t)n0 * kFF;
    for (int k0 = 0; k0 < kFF; k0 += 32) {
      __syncthreads();
#pragma unroll
      for (int r = 0; r < 2; ++r) {
        const int idx = r * 256 + tid;
        const int row = idx >> 2, cg = (idx & 3) * 8;
        GLOBAL_LOAD_LDS16(Ab + (size_t)row * kFF + k0 + cg, &As[idx * 8]);
        GLOBAL_LOAD_LDS16(Bb + (size_t)row * kFF + k0 + cg, &Bs[idx * 8]);
      }
      __syncthreads();
      short8 af[4], bf[4];
#pragma unroll
      for (int i = 0; i < 4; ++i) {
        af[i] = *reinterpret_cast<const short8*>(&As[(wm + i * 16 + fr) * 32 + fc]);
        bf[i] = *reinterpret_cast<const short8*>(&Bs[(wn + i * 16 + fr) * 32 + fc]);
      }
#pragma unroll
      for (int i = 0; i < 4; ++i)
#pragma unroll
        for (int j = 0; j < 4; ++j)
          acc[i][j] = __builtin_amdgcn_mfma_f32_16x16x32_bf16(af[i], bf[j], acc[i][j], 0, 0, 0);
    }
  }
  const int cr = (lane >> 4) * 4, cc = lane & 15;
#pragma unroll
  for (int i = 0; i < 4; ++i) {
#pragma unroll
    for (int r = 0; r < 4; ++r) {
      const int lr = wm + i * 16 + cr + r;
      const int m = m0 + lr;
      const float g = gates[(size_t)m * kE + e];
#pragma unroll
      for (int j = 0; j < 4; ++j) {
        const int gc = n0 + wn + j * 16 + cc;
        const float v = acc[i][j][r] + b2[gc];
        const size_t idx = (size_t)m * kD + gc;
        moe[idx] = (e == 0 ? 0.f : moe[idx]) + g * v;
      }
    }
  }
}

// ----- batched MFMA conv kernels (all 4 experts in one grid) -----
__global__ __launch_bounds__(256) void k_conv1_all(
    const __hip_bfloat16* __restrict__ Hpad, const __hip_bfloat16* __restrict__ W1T,
    const float* __restrict__ b1, __hip_bfloat16* __restrict__ Y1all) {
  __shared__ __align__(16) __hip_bfloat16 As[128 * 32];
  __shared__ __align__(16) __hip_bfloat16 Bs[128 * 32];
  constexpr int NX = kFF / 128;            // 16
  constexpr int NY = kM / 128;             // 64
  constexpr int NWG = kE * NY * NX;        // 4096 (%8==0 -> bijective swizzle)
  int lid = blockIdx.x;
  lid = (lid & 7) * (NWG / 8) + (lid >> 3);  // XCD-aware swizzle
  const int e = lid / (NY * NX);
  const int rem = lid - e * (NY * NX);
  const int by = rem / NX;
  const int bx = rem - by * NX;
  const int tid = threadIdx.x;
  const int m0 = by * 128;
  const int n0 = bx * 128;
  const int b = m0 >> 9;
  const int t0 = m0 & (kT - 1);
  const int arow0 = b * kTP + t0;
  const int w = tid >> 6, lane = tid & 63;
  const int wm = (w >> 1) * 64, wn = (w & 1) * 64;
  f32x4 acc[4][4] = {};
  const int fr = lane & 15, fc = (lane >> 4) * 8;
  for (int kk = 0; kk < 3; ++kk) {
    const __hip_bfloat16* Ab = Hpad + (size_t)(arow0 + kk) * kD;
    const __hip_bfloat16* Bb =
        W1T + ((size_t)e * 3 + kk) * kFF * kD + (size_t)n0 * kD;
    for (int k0 = 0; k0 < kD; k0 += 32) {
      __syncthreads();
#pragma unroll
      for (int r = 0; r < 2; ++r) {
        const int idx = r * 256 + tid;
        const int row = idx >> 2, cg = (idx & 3) * 8;
        GLOBAL_LOAD_LDS16(Ab + (size_t)row * kD + k0 + cg, &As[idx * 8]);
        GLOBAL_LOAD_LDS16(Bb + (size_t)row * kD + k0 + cg, &Bs[idx * 8]);
      }
      __syncthreads();
      short8 af[4], bf[4];
#pragma unroll
      for (int i = 0; i < 4; ++i) {
        af[i] = *reinterpret_cast<const short8*>(&As[(wm + i * 16 + fr) * 32 + fc]);
        bf[i] = *reinterpret_cast<const short8*>(&Bs[(wn + i * 16 + fr) * 32 + fc]);
      }
#pragma unroll
      for (int i = 0; i < 4; ++i)
#pragma unroll
        for (int j = 0; j < 4; ++j)
          acc[i][j] = __builtin_amdgcn_mfma_f32_16x16x32_bf16(af[i], bf[j], acc[i][j], 0, 0, 0);
    }
  }
  __hip_bfloat16* Yb = Y1all + (size_t)e * kY1S;
  const float* b1e = b1 + (size_t)e * kFF;
  const int orow0 = b * kTP + t0 + 1;
  const int cr = (lane >> 4) * 4, cc = lane & 15;
#pragma unroll
  for (int i = 0; i < 4; ++i) {
#pragma unroll
    for (int r = 0; r < 4; ++r) {
      const int lr = wm + i * 16 + cr + r;
#pragma unroll
      for (int j = 0; j < 4; ++j) {
        const int gc = n0 + wn + j * 16 + cc;
        const float v = acc[i][j][r] + b1e[gc];
        Yb[(size_t)(orow0 + lr) * kFF + gc] = __float2bfloat16(fmaxf(v, 0.f));
      }
    }
  }
}

__global__ __launch_bounds__(256) void k_conv2_all(
    const __hip_bfloat16* __restrict__ Y1all, const __hip_bfloat16* __restrict__ W2T,
    const float* __restrict__ b2, const float* __restrict__ gates,
    float* __restrict__ moe) {
  __shared__ __align__(16) __hip_bfloat16 As[128 * 32];
  __shared__ __align__(16) __hip_bfloat16 Bs[128 * 32];
  constexpr int NX = kD / 128;             // 8
  constexpr int NY = kM / 128;             // 64
  constexpr int NWG = kE * NY * NX;        // 2048 (%8==0 -> bijective swizzle)
  int lid = blockIdx.x;
  lid = (lid & 7) * (NWG / 8) + (lid >> 3);  // XCD-aware swizzle
  const int e = lid / (NY * NX);
  const int rem = lid - e * (NY * NX);
  const int by = rem / NX;
  const int bx = rem - by * NX;
  const int tid = threadIdx.x;
  const int m0 = by * 128;
  const int n0 = bx * 128;
  const int b = m0 >> 9;
  const int t0 = m0 & (kT - 1);
  const int arow0 = b * kTP + t0;
  const int w = tid >> 6, lane = tid & 63;
  const int wm = (w >> 1) * 64, wn = (w & 1) * 64;
  f32x4 acc[4][4] = {};
  const int fr = lane & 15, fc = (lane >> 4) * 8;
  const __hip_bfloat16* Ye = Y1all + (size_t)e * kY1S;
  for (int kk = 0; kk < 3; ++kk) {
    const __hip_bfloat16* Ab = Ye + (size_t)(arow0 + kk) * kFF;
    const __hip_bfloat16* Bb =
        W2T + ((size_t)e * 3 + kk) * kD * kFF + (size_t)n0 * kFF;
    for (int k0 = 0; k0 < kFF; k0 += 32) {
      __syncthreads();
#pragma unroll
      for (int r = 0; r < 2; ++r) {
        const int idx = r * 256 + tid;
        const int row = idx >> 2, cg = (idx & 3) * 8;
        GLOBAL_LOAD_LDS16(Ab + (size_t)row * kFF + k0 + cg, &As[idx * 8]);
        GLOBAL_LOAD_LDS16(Bb + (size_t)row * kFF + k0 + cg, &Bs[idx * 8]);
      }
      __syncthreads();
      short8 af[4], bf[4];
#pragma unroll
      for (int i = 0; i < 4; ++i) {
        af[i] = *reinterpret_cast<const short8*>(&As[(wm + i * 16 + fr) * 32 + fc]);
        bf[i] = *reinterpret_cast<const short8*>(&Bs[(wn + i * 16 + fr) * 32 + fc]);
      }
#pragma unroll
      for (int i = 0; i < 4; ++i)
#pragma unroll
        for (int j = 0; j < 4; ++j)
          acc[i][j] = __builtin_amdgcn_mfma_f32_16x16x32_bf16(af[i], bf[j], acc[i][j], 0, 0, 0);
    }
  }
  const float* b2e = b2 + (size_t)e * kD;
  const int cr = (lane >> 4) * 4, cc = lane & 15;
#pragma unroll
  for (int i = 0; i < 4; ++i) {
#pragma unroll
    for (int r = 0; r < 4; ++r) {
      const int lr = wm + i * 16 + cr + r;
      const int m = m0 + lr;
      const float g = gates[(size_t)m * kE + e];
#pragma unroll
      for (int j = 0; j < 4; ++j) {
        const int gc = n0 + wn + j * 16 + cc;
        const float v = acc[i][j][r] + b2e[gc];
        atomicAdd(&moe[(size_t)m * kD + gc], g * v);
      }
    }
  }
}

// ----- small kernels -----
__global__ __launch_bounds__(256) void k_cnt(const int* __restrict__ mask,
                                             float* __restrict__ cnt) {
  __shared__ float red[256];
  const int i = blockIdx.x * 256 + threadIdx.x;
  float v = (float)mask[i];
  v = block_reduce_sum(v, red);
  if (threadIdx.x == 0) atomicAdd(cnt, v);
}

__global__ __launch_bounds__(256) void k_stats(const float* __restrict__ H,
                                               const int* __restrict__ mask,
                                               float* __restrict__ sums,
                                               float* __restrict__ sumsq) {
  const int ch = blockIdx.x * 256 + threadIdx.x;
  const int r0 = blockIdx.y * 64;
  float s = 0.f, q = 0.f;
  for (int r = r0; r < r0 + 64; ++r) {
    if (mask[r]) {
      const float v = H[(size_t)r * kD + ch];
      s += v;
      q += v * v;
    }
  }
  atomicAdd(&sums[ch], s);
  atomicAdd(&sumsq[ch], q);
}

__global__ __launch_bounds__(256) void k_finalize(
    const float* __restrict__ sums, const float* __restrict__ sumsq,
    const float* __restrict__ cntp, const float* __restrict__ bn_g,
    const float* __restrict__ bn_b, float* __restrict__ aa,
    float* __restrict__ cc) {
  const int d = blockIdx.x * 256 + threadIdx.x;
  const float cnt = fmaxf(*cntp, 1.f);
  const float mean = sums[d] / cnt;
  const float var = sumsq[d] / cnt - mean * mean;
  const float istd = rsqrtf(var + 1e-5f);
  const float a = bn_g[d] * istd;
  aa[d] = a;
  cc[d] = bn_b[d] - mean * a;
}

// masked BN + relu + pe -> Hpad (bf16); gate softmax/top2 -> gates, probs
__global__ __launch_bounds__(256) void k_norm_gate(
    const float* __restrict__ H, const int* __restrict__ mask,
    const float* __restrict__ pe, const float* __restrict__ aa,
    const float* __restrict__ cc, const float* __restrict__ gw,
    __hip_bfloat16* __restrict__ Hpad, float* __restrict__ gates,
    float* __restrict__ probs) {
  __shared__ float red[256];
  __shared__ float glog[4];
  const int r = blockIdx.x;
  const int tid = threadIdx.x;
  const int b = r >> 9;
  const int t = r & (kT - 1);
  const bool mv = mask[r] != 0;
  const size_t orow = (size_t)(b * kTP + t + 1) * kD;
  float gl[4] = {0.f, 0.f, 0.f, 0.f};
#pragma unroll
  for (int j = 0; j < 4; ++j) {
    const int d = tid + j * 256;
    float v = H[(size_t)r * kD + d];
    if (mv) v = v * aa[d] + cc[d];
    v = fmaxf(v, 0.f) + pe[(size_t)t * kD + d];
    Hpad[orow + d] = __float2bfloat16(v);
    const float4 g = *reinterpret_cast<const float4*>(gw + (size_t)d * 4);
    gl[0] += v * g.x; gl[1] += v * g.y; gl[2] += v * g.z; gl[3] += v * g.w;
  }
  for (int e = 0; e < 4; ++e) {
    const float s = block_reduce_sum(gl[e], red);
    if (tid == 0) glog[e] = s;
  }
  __syncthreads();
  if (tid == 0) {
    float lg[4] = {glog[0], glog[1], glog[2], glog[3]};
    const float mx = fmaxf(fmaxf(lg[0], lg[1]), fmaxf(lg[2], lg[3]));
    float ex[4], s = 0.f;
#pragma unroll
    for (int e = 0; e < 4; ++e) { ex[e] = expf(lg[e] - mx); s += ex[e]; }
    int i0 = 0;
    for (int e = 1; e < 4; ++e) if (lg[e] > lg[i0]) i0 = e;
    int i1 = -1;
    for (int e = 0; e < 4; ++e) {
      if (e == i0) continue;
      if (i1 < 0 || lg[e] > lg[i1]) i1 = e;
    }
    const float g0 = 1.f / (1.f + expf(lg[i1] - lg[i0]));
    float gv[4] = {0.f, 0.f, 0.f, 0.f};
    gv[i0] = g0;
    gv[i1] = 1.f - g0;
    *reinterpret_cast<float4*>(gates + (size_t)r * 4) =
        make_float4(gv[0], gv[1], gv[2], gv[3]);
    const float inv_s = 1.f / s;
    *reinterpret_cast<float4*>(probs + (size_t)r * 4) =
        make_float4(ex[0] * inv_s, ex[1] * inv_s, ex[2] * inv_s, ex[3] * inv_s);
  }
}

__global__ __launch_bounds__(256) void k_ln(
    const float* __restrict__ moe, const float* __restrict__ g,
    const float* __restrict__ b, float* __restrict__ feat,
    float* __restrict__ featn, __hip_bfloat16* __restrict__ featb) {
  __shared__ float red[256];
  const int r = blockIdx.x;
  const int tid = threadIdx.x;
  float v[4];
  float s = 0.f, q = 0.f;
#pragma unroll
  for (int j = 0; j < 4; ++j) {
    v[j] = moe[(size_t)r * kD + tid + j * 256];
    s += v[j];
    q += v[j] * v[j];
  }
  const float sum = block_reduce_sum(s, red);
  const float mu = sum * (1.f / kD);
  const float sq = block_reduce_sum(q, red);
  const float var = sq * (1.f / kD) - mu * mu;
  const float istd = rsqrtf(var + 1e-6f);
  float f[4];
  float fs = 0.f;
#pragma unroll
  for (int j = 0; j < 4; ++j) {
    const int d = tid + j * 256;
    f[j] = (v[j] - mu) * istd * g[d] + b[d];
    feat[(size_t)r * kD + d] = f[j];
    featb[(size_t)r * kD + d] = __float2bfloat16(f[j]);
    fs += f[j] * f[j];
  }
  const float nrm2 = block_reduce_sum(fs, red);
  const float scale = 1.f / fmaxf(sqrtf(nrm2), 1e-12f);
#pragma unroll
  for (int j = 0; j < 4; ++j) {
    const int d = tid + j * 256;
    featn[(size_t)r * kD + d] = f[j] * scale;
  }
}

__global__ __launch_bounds__(256) void k_softmax(
    const float* __restrict__ logits, float* __restrict__ logp,
    float* __restrict__ p) {
  __shared__ float red[256];
  const int r = blockIdx.x;
  const int tid = threadIdx.x;
  float lv[5];
  float mx = -1e30f;
#pragma unroll
  for (int j = 0; j < 5; ++j) {
    const int c = tid + j * 256;
    if (c < kCLS) {
      lv[j] = logits[(size_t)r * kCLS + c];
      mx = fmaxf(mx, lv[j]);
    }
  }
  mx = block_reduce_max(mx, red);
  float s = 0.f;
#pragma unroll
  for (int j = 0; j < 5; ++j) {
    const int c = tid + j * 256;
    if (c < kCLS) s += expf(lv[j] - mx);
  }
  s = block_reduce_sum(s, red);
  const float lse = mx + logf(s);
#pragma unroll
  for (int j = 0; j < 5; ++j) {
    const int c = tid + j * 256;
    if (c < kCLS) {
      const float lp = lv[j] - lse;
      logp[(size_t)r * kCLS + c] = lp;
      p[(size_t)r * kCLS + c] = expf(lp);
    }
  }
}

// aux = E * sum_e (frac_e * imp_e); single block, no global atomics
__global__ __launch_bounds__(256) void k_aux(const float* __restrict__ probs,
                                             const float* __restrict__ gates,
                                             float* __restrict__ out) {
  __shared__ float red[256];
  const int tid = threadIdx.x;
  float si[4] = {0.f, 0.f, 0.f, 0.f};
  float sf[4] = {0.f, 0.f, 0.f, 0.f};
  for (int i = tid; i < kM; i += 256) {
    const float4 p = *reinterpret_cast<const float4*>(probs + (size_t)i * 4);
    const float4 g = *reinterpret_cast<const float4*>(gates + (size_t)i * 4);
    si[0] += p.x; si[1] += p.y; si[2] += p.z; si[3] += p.w;
    sf[0] += (g.x > 0.f) ? 1.f : 0.f;
    sf[1] += (g.y > 0.f) ? 1.f : 0.f;
    sf[2] += (g.z > 0.f) ? 1.f : 0.f;
    sf[3] += (g.w > 0.f) ? 1.f : 0.f;
  }
  float tot = 0.f;
  for (int e = 0; e < 4; ++e) {
    const float S = block_reduce_sum(si[e], red);
    const float F = block_reduce_sum(sf[e], red);
    tot += (F / (float)kM) * (S / (float)kM);
  }
  if (tid == 0) out[0] = (float)kE * tot;
}

}  // namespace

extern "C" void kernel_launch(void* const* d_in, const int* in_sizes, int n_in,
                              void* d_out, int out_size, void* d_ws,
                              size_t ws_size, hipStream_t stream) {
  const float* x     = (const float*)d_in[0];
  const int*   mask  = (const int*)d_in[1];
  const float* fc1_w = (const float*)d_in[2];
  const float* fc1_b = (const float*)d_in[3];
  const float* bn_g  = (const float*)d_in[4];
  const float* bn_b  = (const float*)d_in[5];
  const float* pe    = (const float*)d_in[6];
  const float* gw    = (const float*)d_in[7];
  const float* ew1   = (const float*)d_in[8];
  const float* eb1   = (const float*)d_in[9];
  const float* ew2   = (const float*)d_in[10];
  const float* eb2   = (const float*)d_in[11];
  const float* ln_g  = (const float*)d_in[12];
  const float* ln_b  = (const float*)d_in[13];
  const float* out_w = (const float*)d_in[14];
  const float* out_b = (const float*)d_in[15];

  float* ws = (float*)d_ws;

  float* outf   = (float*)d_out;
  float* feat   = outf;
  float* featn  = outf + kBTD;
  float* logits = outf + 2 * kBTD;
  float* logp   = logits + kBTC;
  float* pprob  = logp + kBTC;
  float* aux    = pprob + kBTC;

  const bool batched = ws_size >= BW_END * sizeof(float);

  if (batched) {
    float* H     = ws + BW_H;                       // fc1 out; later MOE
    __hip_bfloat16* HPAD  = (__hip_bfloat16*)(ws + BW_HPAD);
    __hip_bfloat16* Y1ALL = (__hip_bfloat16*)(ws + BW_Y1);
    // aliases of the Y1 region (disjoint lifetimes):
    __hip_bfloat16* XHI   = Y1ALL;                  // fc1 phase
    __hip_bfloat16* XLO   = XHI + kBTD;             // fc1 phase
    __hip_bfloat16* FEATB = Y1ALL;                  // epilogue
    __hip_bfloat16* W1T   = (__hip_bfloat16*)(ws + BW_W1T);
    __hip_bfloat16* W2T   = (__hip_bfloat16*)(ws + BW_W2T);
    float* GATES = ws + BW_GATES;
    float* PROBS = ws + BW_PROBS;
    __hip_bfloat16* W1HI = (__hip_bfloat16*)(ws + BW_W1HI);
    __hip_bfloat16* W1LO = (__hip_bfloat16*)(ws + BW_W1LO);
    __hip_bfloat16* OWB  = (__hip_bfloat16*)(ws + BW_OWB);
    float* SUMS  = ws + BW_SUMS;
    float* MOE   = H;

    k_zero<<<dim3((WS_ZERON + 255) / 256), 256, 0, stream>>>(SUMS, WS_ZERON);
    k_split<<<dim3((int)(kBTD / 4 + 255) / 256), 256, 0, stream>>>(
        x, XHI, XLO, (int)(kBTD / 4));
    k_split<<<dim3((kD * kD / 4 + 255) / 256), 256, 0, stream>>>(
        fc1_w, W1HI, W1LO, kD * kD / 4);
    k_fc1_mfma<<<dim3(kD / 128, kM / 128), 256, 0, stream>>>(
        XHI, XLO, W1HI, W1LO, fc1_b, H);
    // after fc1, Y1 region is free: zero sentinel rows of Hpad + 4 Y1 bufs
    k_zero_bnd_all<<<dim3(2 * kB * (1 + kE)), 256, 0, stream>>>(HPAD, Y1ALL);
    // all 8 conv weight transposes in one launch
    k_wt_all<<<dim3((int)(((size_t)kE * kFF * kD + 255) / 256)), 256, 0,
               stream>>>(ew1, ew2, W1T, W2T);
    k_cnt<<<dim3(kM / 256), 256, 0, stream>>>(mask, ws + BW_CNT);
    k_stats<<<dim3(kD / 256, kM / 64), 256, 0, stream>>>(H, mask, SUMS,
                                                         ws + BW_SUMSQ);
    k_finalize<<<dim3(kD / 256), 256, 0, stream>>>(
        SUMS, ws + BW_SUMSQ, ws + BW_CNT, bn_g, bn_b, ws + BW_AA, ws + BW_CC);
    k_norm_gate<<<dim3(kM), 256, 0, stream>>>(H, mask, pe, ws + BW_AA,
                                              ws + BW_CC, gw, HPAD, GATES,
                                              PROBS);
    // H is dead now; zero MOE (alias of H) for atomic accumulation
    k_zero<<<dim3((int)((kBTD + 255) / 256)), 256, 0, stream>>>(MOE,
                                                                (int)kBTD);
    k_conv1_all<<<dim3(kE * (kM / 128) * (kFF / 128)), 256, 0, stream>>>(
        HPAD, W1T, eb1, Y1ALL);
    k_conv2_all<<<dim3(kE * (kM / 128) * (kD / 128)), 256, 0, stream>>>(
        Y1ALL, W2T, eb2, GATES, MOE);
    k_ln<<<dim3(kM), 256, 0, stream>>>(MOE, ln_g, ln_b, feat, featn, FEATB);
    k_wcast_pad<<<dim3((int)((size_t)kCLSP * kD + 255) / 256), 256, 0,
                  stream>>>(out_w, OWB);
    k_cls_mfma<<<dim3(kCLSP / 128, kM / 128), 256, 0, stream>>>(FEATB, OWB,
                                                                out_b, logits);
    k_softmax<<<dim3(kM), 256, 0, stream>>>(logits, logp, pprob);
    k_aux<<<1, 256, 0, stream>>>(PROBS, GATES, aux);
    return;
  }

  // ---------------- fallback: previous verified serial path ----------------
  float* H     = ws + WS_H;
  __hip_bfloat16* HPAD  = (__hip_bfloat16*)(ws + WS_HPAD);
  __hip_bfloat16* Y1PAD = (__hip_bfloat16*)(ws + WS_Y1P);
  __hip_bfloat16* XHI   = (__hip_bfloat16*)(ws + WS_Y1P);
  __hip_bfloat16* XLO   = XHI + kBTD;
  __hip_bfloat16* FEATB = (__hip_bfloat16*)(ws + WS_Y1P);
  __hip_bfloat16* W1T   = (__hip_bfloat16*)(ws + WS_W1T);
  __hip_bfloat16* W2T   = (__hip_bfloat16*)(ws + WS_W2T);
  float* GATES = ws + WS_GATES;
  float* PROBS = ws + WS_PROBS;
  __hip_bfloat16* W1HI = (__hip_bfloat16*)(ws + WS_W1HI);
  __hip_bfloat16* W1LO = (__hip_bfloat16*)(ws + WS_W1LO);
  __hip_bfloat16* OWB  = (__hip_bfloat16*)(ws + WS_OWB);
  float* SUMS  = ws + WS_SUMS;
  float* SUMSQ = ws + WS_SUMSQ;
  float* CNT   = ws + WS_CNT;
  float* AA    = ws + WS_AA;
  float* CC    = ws + WS_CC;
  float* MOE   = H;

  k_zero<<<dim3((WS_ZERON + 255) / 256), 256, 0, stream>>>(SUMS, WS_ZERON);
  k_split<<<dim3((int)(kBTD / 4 + 255) / 256), 256, 0, stream>>>(x, XHI, XLO,
                                                                 (int)(kBTD / 4));
  k_split<<<dim3((kD * kD / 4 + 255) / 256), 256, 0, stream>>>(
      fc1_w, W1HI, W1LO, kD * kD / 4);
  k_fc1_mfma<<<dim3(kD / 128, kM / 128), 256, 0, stream>>>(XHI, XLO, W1HI,
                                                           W1LO, fc1_b, H);
  k_zero_bnd<<<dim3(2 * kB), 256, 0, stream>>>(HPAD, Y1PAD);
  k_cnt<<<dim3(kM / 256), 256, 0, stream>>>(mask, CNT);
  k_stats<<<dim3(kD / 256, kM / 64), 256, 0, stream>>>(H, mask, SUMS, SUMSQ);
  k_finalize<<<dim3(kD / 256), 256, 0, stream>>>(SUMS, SUMSQ, CNT, bn_g, bn_b,
                                                 AA, CC);
  k_norm_gate<<<dim3(kM), 256, 0, stream>>>(H, mask, pe, AA, CC, gw, HPAD,
                                            GATES, PROBS);
  for (int e = 0; e < kE; ++e) {
    k_wt<<<dim3((kFF * kD + 255) / 256), 256, 0, stream>>>(
        ew1 + (size_t)e * kFF * kD * 3, W1T, kFF * kD);
    k_wt<<<dim3((kD * kFF + 255) / 256), 256, 0, stream>>>(
        ew2 + (size_t)e * kD * kFF * 3, W2T, kD * kFF);
    k_conv1_mfma<<<dim3(kFF / 128, kM / 128), 256, 0, stream>>>(
        HPAD, W1T, eb1 + (size_t)e * kFF, Y1PAD);
    k_conv2_mfma<<<dim3(kD / 128, kM / 128), 256, 0, stream>>>(
        Y1PAD, W2T, eb2 + (size_t)e * kD, GATES, e, MOE);
  }
  k_ln<<<dim3(kM), 256, 0, stream>>>(MOE, ln_g, ln_b, feat, featn, FEATB);
  k_wcast_pad<<<dim3((int)((size_t)kCLSP * kD + 255) / 256), 256, 0, stream>>>(
      out_w, OWB);
  k_cls_mfma<<<dim3(kCLSP / 128, kM / 128), 256, 0, stream>>>(FEATB, OWB,
                                                              out_b, logits);
  k_softmax<<<dim3(kM), 256, 0, stream>>>(logits, logp, pprob);
  k_aux<<<1, 256, 0, stream>>>(PROBS, GATES, aux);
}

// Round 2
// 1369.142 us; speedup vs baseline: 1.3125x; 1.2903x over previous
//
#include <hip/hip_runtime.h>
#include <hip/hip_bf16.h>

// ---------------------------------------------------------------------------
// VisualHead forward. Round 5:
//  - conv1/conv2 rewritten as 256x256 8-phase counted-vmcnt MFMA pipeline
//    (T2 st_16x32 LDS swizzle + T3/T4 half-tile-granular counted vmcnt(4)
//    pipeline + T5 setprio), 512 threads, 128 KiB LDS, 1 block/CU.
//    Phase = wait vmcnt(4); s_barrier; sched_barrier; stage 1 half-tile of
//    tile tau+1; ds_read frags; 16 MFMA. Taps folded into K-tile loop.
//  - Everything else (fc1 split-bf16 MFMA, classifier, norm/gate/ln/softmax,
//    expert-batched weight transform, atomicAdd MOE accum) unchanged.
//  - Serial fallback retained for small workspaces.
// ---------------------------------------------------------------------------

namespace {

constexpr int kB = 16, kT = 512, kD = 1024, kFF = 2048, kE = 4, kCLS = 1200;
constexpr int kM = kB * kT;                    // 8192
constexpr int kTP = kT + 2;                    // padded seq len
constexpr int kCLSP = 1280;                    // padded classifier rows
constexpr size_t kBTD = (size_t)kM * kD;
constexpr size_t kBTC = (size_t)kM * kCLS;
constexpr size_t kY1S = (size_t)kB * kTP * kFF;   // per-expert Y1 elems (bf16)
constexpr size_t kTapStride = (size_t)kFF * kD;   // 2097152 (both convs)

// ---------------- serial (fallback) workspace layout (float units) --------
constexpr size_t WS_H     = 0;
constexpr size_t WS_HPAD  = WS_H + kBTD;
constexpr size_t WS_Y1P   = WS_HPAD + (size_t)kB * kTP * kD / 2;
constexpr size_t WS_W1T   = WS_Y1P + (size_t)kB * kTP * kFF / 2;
constexpr size_t WS_W2T   = WS_W1T + (size_t)3 * kFF * kD / 2;
constexpr size_t WS_GATES = WS_W2T + (size_t)3 * kD * kFF / 2;
constexpr size_t WS_PROBS = WS_GATES + (size_t)kM * kE;
constexpr size_t WS_W1HI  = WS_PROBS + (size_t)kM * kE;
constexpr size_t WS_W1LO  = WS_W1HI + (size_t)kD * kD / 2;
constexpr size_t WS_OWB   = WS_W1LO + (size_t)kD * kD / 2;
constexpr size_t WS_SUMS  = WS_OWB + (size_t)kCLSP * kD / 2;
constexpr size_t WS_SUMSQ = WS_SUMS + kD;
constexpr size_t WS_CNT   = WS_SUMSQ + kD;
constexpr size_t WS_AA    = WS_CNT + 1;
constexpr size_t WS_CC    = WS_AA + kD;
constexpr int WS_ZERON = (int)(2 * kD + 1);

// ---------------- batched workspace layout (float units) -------------------
constexpr size_t BW_H     = 0;
constexpr size_t BW_HPAD  = BW_H + kBTD;
constexpr size_t BW_Y1    = BW_HPAD + (size_t)kB * kTP * kD / 2;
constexpr size_t BW_W1T   = BW_Y1 + (size_t)kE * kY1S / 2;
constexpr size_t BW_W2T   = BW_W1T + (size_t)kE * 3 * kFF * kD / 2;
constexpr size_t BW_GATES = BW_W2T + (size_t)kE * 3 * kD * kFF / 2;
constexpr size_t BW_PROBS = BW_GATES + (size_t)kM * kE;
constexpr size_t BW_W1HI  = BW_PROBS + (size_t)kM * kE;
constexpr size_t BW_W1LO  = BW_W1HI + (size_t)kD * kD / 2;
constexpr size_t BW_OWB   = BW_W1LO + (size_t)kD * kD / 2;
constexpr size_t BW_SUMS  = BW_OWB + (size_t)kCLSP * kD / 2;
constexpr size_t BW_SUMSQ = BW_SUMS + kD;
constexpr size_t BW_CNT   = BW_SUMSQ + kD;
constexpr size_t BW_AA    = BW_CNT + 1;
constexpr size_t BW_CC    = BW_AA + kD;
constexpr size_t BW_END   = BW_CC + kD;

typedef __attribute__((ext_vector_type(8))) short short8;
typedef __attribute__((ext_vector_type(4))) float f32x4;

#define GLOBAL_LOAD_LDS16(gp, lp)                                          \
  __builtin_amdgcn_global_load_lds(                                        \
      (const __attribute__((address_space(1))) void*)(gp),                 \
      (__attribute__((address_space(3))) void*)(lp), 16, 0, 0)

__device__ __forceinline__ float block_reduce_sum(float v, float* red) {
  const int tid = threadIdx.x;
  __syncthreads();
  red[tid] = v;
  __syncthreads();
  for (int s = 128; s > 0; s >>= 1) {
    if (tid < s) red[tid] += red[tid + s];
    __syncthreads();
  }
  return red[0];
}

__device__ __forceinline__ float block_reduce_max(float v, float* red) {
  const int tid = threadIdx.x;
  __syncthreads();
  red[tid] = v;
  __syncthreads();
  for (int s = 128; s > 0; s >>= 1) {
    if (tid < s) red[tid] = fmaxf(red[tid], red[tid + s]);
    __syncthreads();
  }
  return red[0];
}

__global__ void k_zero(float* __restrict__ p, int n) {
  int i = blockIdx.x * 256 + threadIdx.x;
  if (i < n) p[i] = 0.f;
}

// zero sentinel rows (t=-1, t=T) of Hpad and Y1pad (serial path)
__global__ void k_zero_bnd(__hip_bfloat16* __restrict__ Hpad,
                           __hip_bfloat16* __restrict__ Y1pad) {
  const int b = blockIdx.x >> 1;
  const int row = b * kTP + ((blockIdx.x & 1) ? (kTP - 1) : 0);
  const __hip_bfloat16 z = __float2bfloat16(0.f);
  for (int d = threadIdx.x; d < kD; d += 256) Hpad[(size_t)row * kD + d] = z;
  for (int d = threadIdx.x; d < kFF; d += 256) Y1pad[(size_t)row * kFF + d] = z;
}

// zero sentinel rows of Hpad and all 4 expert Y1 buffers (batched path)
__global__ void k_zero_bnd_all(__hip_bfloat16* __restrict__ Hpad,
                               __hip_bfloat16* __restrict__ Y1all) {
  const int g = blockIdx.x;            // [0, 2*kB*(1+kE))
  const int which = g / (2 * kB);      // 0: Hpad, 1..4: expert e = which-1
  const int r = g % (2 * kB);
  const int b = r >> 1;
  const int row = b * kTP + ((r & 1) ? (kTP - 1) : 0);
  const __hip_bfloat16 z = __float2bfloat16(0.f);
  if (which == 0) {
    for (int d = threadIdx.x; d < kD; d += 256) Hpad[(size_t)row * kD + d] = z;
  } else {
    __hip_bfloat16* Y = Y1all + (size_t)(which - 1) * kY1S;
    for (int d = threadIdx.x; d < kFF; d += 256) Y[(size_t)row * kFF + d] = z;
  }
}

// fp32 -> (hi, lo) bf16 split; 4 elems/thread
__global__ __launch_bounds__(256) void k_split(const float* __restrict__ src,
                                               __hip_bfloat16* __restrict__ hi,
                                               __hip_bfloat16* __restrict__ lo,
                                               int n4) {
  const int i = blockIdx.x * 256 + threadIdx.x;
  if (i >= n4) return;
  const float4 v = *reinterpret_cast<const float4*>(src + (size_t)i * 4);
  const float vv[4] = {v.x, v.y, v.z, v.w};
  unsigned short h[4], l[4];
#pragma unroll
  for (int j = 0; j < 4; ++j) {
    __hip_bfloat16 hb = __float2bfloat16(vv[j]);
    __hip_bfloat16 lb = __float2bfloat16(vv[j] - __bfloat162float(hb));
    h[j] = *reinterpret_cast<unsigned short*>(&hb);
    l[j] = *reinterpret_cast<unsigned short*>(&lb);
  }
  *reinterpret_cast<short4*>(hi + (size_t)i * 4) =
      make_short4(h[0], h[1], h[2], h[3]);
  *reinterpret_cast<short4*>(lo + (size_t)i * 4) =
      make_short4(l[0], l[1], l[2], l[3]);
}

// out_w [1200,D] fp32 -> OWB [1280,D] bf16, zero padded rows
__global__ __launch_bounds__(256) void k_wcast_pad(
    const float* __restrict__ w, __hip_bfloat16* __restrict__ dst) {
  const size_t i = (size_t)blockIdx.x * 256 + threadIdx.x;
  if (i >= (size_t)kCLSP * kD) return;
  const size_t r = i / kD;
  dst[i] = __float2bfloat16(r < kCLS ? w[i] : 0.f);
}

// conv weight transpose+cast (serial path): [O][I][3] fp32 -> [3][O][I] bf16
__global__ __launch_bounds__(256) void k_wt(const float* __restrict__ src,
                                            __hip_bfloat16* __restrict__ dst,
                                            int n) {
  const int i = blockIdx.x * 256 + threadIdx.x;
  if (i >= n) return;
  const float* s = src + (size_t)i * 3;
  dst[i] = __float2bfloat16(s[0]);
  dst[(size_t)n + i] = __float2bfloat16(s[1]);
  dst[(size_t)2 * n + i] = __float2bfloat16(s[2]);
}

// batched weight transpose+cast for all experts, both convs
__global__ __launch_bounds__(256) void k_wt_all(const float* __restrict__ ew1,
                                                const float* __restrict__ ew2,
                                                __hip_bfloat16* __restrict__ W1T,
                                                __hip_bfloat16* __restrict__ W2T) {
  const size_t n = (size_t)kFF * kD;
  const size_t total = (size_t)kE * n;
  const size_t i = (size_t)blockIdx.x * 256 + threadIdx.x;
  if (i >= total) return;
  const size_t e = i / n, j = i - e * n;
  {
    const float* s = ew1 + (e * n + j) * 3;
    __hip_bfloat16* d = W1T + e * 3 * n;
    d[j] = __float2bfloat16(s[0]);
    d[n + j] = __float2bfloat16(s[1]);
    d[2 * n + j] = __float2bfloat16(s[2]);
  }
  {
    const float* s = ew2 + (e * n + j) * 3;
    __hip_bfloat16* d = W2T + e * 3 * n;
    d[j] = __float2bfloat16(s[0]);
    d[n + j] = __float2bfloat16(s[1]);
    d[2 * n + j] = __float2bfloat16(s[2]);
  }
}

// ----- fc1: H = (Xhi+Xlo) @ (Whi+Wlo)^T + b, via hi*hi + lo*hi + hi*lo -----
__global__ __launch_bounds__(256) void k_fc1_mfma(
    const __hip_bfloat16* __restrict__ Xhi, const __hip_bfloat16* __restrict__ Xlo,
    const __hip_bfloat16* __restrict__ Whi, const __hip_bfloat16* __restrict__ Wlo,
    const float* __restrict__ bias, float* __restrict__ H) {
  __shared__ __align__(16) __hip_bfloat16 As[128 * 32];
  __shared__ __align__(16) __hip_bfloat16 Bs[128 * 32];
  const int tid = threadIdx.x;
  const int m0 = blockIdx.y * 128;
  const int n0 = blockIdx.x * 128;
  const int w = tid >> 6, lane = tid & 63;
  const int wm = (w >> 1) * 64, wn = (w & 1) * 64;
  f32x4 acc[4][4] = {};
  const int fr = lane & 15, fc = (lane >> 4) * 8;
  const __hip_bfloat16* Aps[3] = {Xhi, Xlo, Xhi};
  const __hip_bfloat16* Bps[3] = {Whi, Whi, Wlo};
  for (int p = 0; p < 3; ++p) {
    const __hip_bfloat16* Ab = Aps[p] + (size_t)m0 * kD;
    const __hip_bfloat16* Bb = Bps[p] + (size_t)n0 * kD;
    for (int k0 = 0; k0 < kD; k0 += 32) {
      __syncthreads();
#pragma unroll
      for (int r = 0; r < 2; ++r) {
        const int idx = r * 256 + tid;
        const int row = idx >> 2, cg = (idx & 3) * 8;
        GLOBAL_LOAD_LDS16(Ab + (size_t)row * kD + k0 + cg, &As[idx * 8]);
        GLOBAL_LOAD_LDS16(Bb + (size_t)row * kD + k0 + cg, &Bs[idx * 8]);
      }
      __syncthreads();
      short8 af[4], bf[4];
#pragma unroll
      for (int i = 0; i < 4; ++i) {
        af[i] = *reinterpret_cast<const short8*>(&As[(wm + i * 16 + fr) * 32 + fc]);
        bf[i] = *reinterpret_cast<const short8*>(&Bs[(wn + i * 16 + fr) * 32 + fc]);
      }
#pragma unroll
      for (int i = 0; i < 4; ++i)
#pragma unroll
        for (int j = 0; j < 4; ++j)
          acc[i][j] = __builtin_amdgcn_mfma_f32_16x16x32_bf16(af[i], bf[j], acc[i][j], 0, 0, 0);
    }
  }
  const int cr = (lane >> 4) * 4, cc = lane & 15;
#pragma unroll
  for (int i = 0; i < 4; ++i) {
#pragma unroll
    for (int r = 0; r < 4; ++r) {
      const int m = m0 + wm + i * 16 + cr + r;
#pragma unroll
      for (int j = 0; j < 4; ++j) {
        const int gc = n0 + wn + j * 16 + cc;
        H[(size_t)m * kD + gc] = acc[i][j][r] + bias[gc];
      }
    }
  }
}

// ----- classifier: logits = featb @ OWB^T + out_b (N padded to 1280) -----
__global__ __launch_bounds__(256) void k_cls_mfma(
    const __hip_bfloat16* __restrict__ Fb, const __hip_bfloat16* __restrict__ Wb,
    const float* __restrict__ bias, float* __restrict__ logits) {
  __shared__ __align__(16) __hip_bfloat16 As[128 * 32];
  __shared__ __align__(16) __hip_bfloat16 Bs[128 * 32];
  const int tid = threadIdx.x;
  const int m0 = blockIdx.y * 128;
  const int n0 = blockIdx.x * 128;
  const int w = tid >> 6, lane = tid & 63;
  const int wm = (w >> 1) * 64, wn = (w & 1) * 64;
  f32x4 acc[4][4] = {};
  const int fr = lane & 15, fc = (lane >> 4) * 8;
  const __hip_bfloat16* Ab = Fb + (size_t)m0 * kD;
  const __hip_bfloat16* Bb = Wb + (size_t)n0 * kD;
  for (int k0 = 0; k0 < kD; k0 += 32) {
    __syncthreads();
#pragma unroll
    for (int r = 0; r < 2; ++r) {
      const int idx = r * 256 + tid;
      const int row = idx >> 2, cg = (idx & 3) * 8;
      GLOBAL_LOAD_LDS16(Ab + (size_t)row * kD + k0 + cg, &As[idx * 8]);
      GLOBAL_LOAD_LDS16(Bb + (size_t)row * kD + k0 + cg, &Bs[idx * 8]);
    }
    __syncthreads();
    short8 af[4], bf[4];
#pragma unroll
    for (int i = 0; i < 4; ++i) {
      af[i] = *reinterpret_cast<const short8*>(&As[(wm + i * 16 + fr) * 32 + fc]);
      bf[i] = *reinterpret_cast<const short8*>(&Bs[(wn + i * 16 + fr) * 32 + fc]);
    }
#pragma unroll
    for (int i = 0; i < 4; ++i)
#pragma unroll
      for (int j = 0; j < 4; ++j)
        acc[i][j] = __builtin_amdgcn_mfma_f32_16x16x32_bf16(af[i], bf[j], acc[i][j], 0, 0, 0);
  }
  const int cr = (lane >> 4) * 4, cc = lane & 15;
#pragma unroll
  for (int i = 0; i < 4; ++i) {
#pragma unroll
    for (int r = 0; r < 4; ++r) {
      const int m = m0 + wm + i * 16 + cr + r;
#pragma unroll
      for (int j = 0; j < 4; ++j) {
        const int gc = n0 + wn + j * 16 + cc;
        if (gc < kCLS) logits[(size_t)m * kCLS + gc] = acc[i][j][r] + bias[gc];
      }
    }
  }
}

// ----- serial-path MFMA conv kernels (fallback) -----
__global__ __launch_bounds__(256) void k_conv1_mfma(
    const __hip_bfloat16* __restrict__ Hpad, const __hip_bfloat16* __restrict__ W1T,
    const float* __restrict__ b1, __hip_bfloat16* __restrict__ Y1pad) {
  __shared__ __align__(16) __hip_bfloat16 As[128 * 32];
  __shared__ __align__(16) __hip_bfloat16 Bs[128 * 32];
  const int tid = threadIdx.x;
  const int m0 = blockIdx.y * 128;
  const int n0 = blockIdx.x * 128;
  const int b = m0 >> 9;
  const int t0 = m0 & (kT - 1);
  const int arow0 = b * kTP + t0;
  const int w = tid >> 6, lane = tid & 63;
  const int wm = (w >> 1) * 64, wn = (w & 1) * 64;
  f32x4 acc[4][4] = {};
  const int fr = lane & 15, fc = (lane >> 4) * 8;
  for (int kk = 0; kk < 3; ++kk) {
    const __hip_bfloat16* Ab = Hpad + (size_t)(arow0 + kk) * kD;
    const __hip_bfloat16* Bb = W1T + (size_t)kk * kFF * kD + (size_t)n0 * kD;
    for (int k0 = 0; k0 < kD; k0 += 32) {
      __syncthreads();
#pragma unroll
      for (int r = 0; r < 2; ++r) {
        const int idx = r * 256 + tid;
        const int row = idx >> 2, cg = (idx & 3) * 8;
        GLOBAL_LOAD_LDS16(Ab + (size_t)row * kD + k0 + cg, &As[idx * 8]);
        GLOBAL_LOAD_LDS16(Bb + (size_t)row * kD + k0 + cg, &Bs[idx * 8]);
      }
      __syncthreads();
      short8 af[4], bf[4];
#pragma unroll
      for (int i = 0; i < 4; ++i) {
        af[i] = *reinterpret_cast<const short8*>(&As[(wm + i * 16 + fr) * 32 + fc]);
        bf[i] = *reinterpret_cast<const short8*>(&Bs[(wn + i * 16 + fr) * 32 + fc]);
      }
#pragma unroll
      for (int i = 0; i < 4; ++i)
#pragma unroll
        for (int j = 0; j < 4; ++j)
          acc[i][j] = __builtin_amdgcn_mfma_f32_16x16x32_bf16(af[i], bf[j], acc[i][j], 0, 0, 0);
    }
  }
  const int orow0 = b * kTP + t0 + 1;
  const int cr = (lane >> 4) * 4, cc = lane & 15;
#pragma unroll
  for (int i = 0; i < 4; ++i) {
#pragma unroll
    for (int r = 0; r < 4; ++r) {
      const int lr = wm + i * 16 + cr + r;
#pragma unroll
      for (int j = 0; j < 4; ++j) {
        const int gc = n0 + wn + j * 16 + cc;
        const float v = acc[i][j][r] + b1[gc];
        Y1pad[(size_t)(orow0 + lr) * kFF + gc] = __float2bfloat16(fmaxf(v, 0.f));
      }
    }
  }
}

__global__ __launch_bounds__(256) void k_conv2_mfma(
    const __hip_bfloat16* __restrict__ Y1pad, const __hip_bfloat16* __restrict__ W2T,
    const float* __restrict__ b2, const float* __restrict__ gates,
    int e, float* __restrict__ moe) {
  __shared__ __align__(16) __hip_bfloat16 As[128 * 32];
  __shared__ __align__(16) __hip_bfloat16 Bs[128 * 32];
  const int tid = threadIdx.x;
  const int m0 = blockIdx.y * 128;
  const int n0 = blockIdx.x * 128;
  const int b = m0 >> 9;
  const int t0 = m0 & (kT - 1);
  const int arow0 = b * kTP + t0;
  const int w = tid >> 6, lane = tid & 63;
  const int wm = (w >> 1) * 64, wn = (w & 1) * 64;
  f32x4 acc[4][4] = {};
  const int fr = lane & 15, fc = (lane >> 4) * 8;
  for (int kk = 0; kk < 3; ++kk) {
    const __hip_bfloat16* Ab = Y1pad + (size_t)(arow0 + kk) * kFF;
    const __hip_bfloat16* Bb = W2T + (size_t)kk * kD * kFF + (size_t)n0 * kFF;
    for (int k0 = 0; k0 < kFF; k0 += 32) {
      __syncthreads();
#pragma unroll
      for (int r = 0; r < 2; ++r) {
        const int idx = r * 256 + tid;
        const int row = idx >> 2, cg = (idx & 3) * 8;
        GLOBAL_LOAD_LDS16(Ab + (size_t)row * kFF + k0 + cg, &As[idx * 8]);
        GLOBAL_LOAD_LDS16(Bb + (size_t)row * kFF + k0 + cg, &Bs[idx * 8]);
      }
      __syncthreads();
      short8 af[4], bf[4];
#pragma unroll
      for (int i = 0; i < 4; ++i) {
        af[i] = *reinterpret_cast<const short8*>(&As[(wm + i * 16 + fr) * 32 + fc]);
        bf[i] = *reinterpret_cast<const short8*>(&Bs[(wn + i * 16 + fr) * 32 + fc]);
      }
#pragma unroll
      for (int i = 0; i < 4; ++i)
#pragma unroll
        for (int j = 0; j < 4; ++j)
          acc[i][j] = __builtin_amdgcn_mfma_f32_16x16x32_bf16(af[i], bf[j], acc[i][j], 0, 0, 0);
    }
  }
  const int cr = (lane >> 4) * 4, cc = lane & 15;
#pragma unroll
  for (int i = 0; i < 4; ++i) {
#pragma unroll
    for (int r = 0; r < 4; ++r) {
      const int lr = wm + i * 16 + cr + r;
      const int m = m0 + lr;
      const float g = gates[(size_t)m * kE + e];
#pragma unroll
      for (int j = 0; j < 4; ++j) {
        const int gc = n0 + wn + j * 16 + cc;
        const float v = acc[i][j][r] + b2[gc];
        const size_t idx = (size_t)m * kD + gc;
        moe[idx] = (e == 0 ? 0.f : moe[idx]) + g * v;
      }
    }
  }
}

// ---------------------------------------------------------------------------
// 8-phase 256x256 conv kernel (both convs, templated).
//  - 512 threads = 8 waves (2M x 4N); per-wave C = 128x64 split into four
//    64x32 quadrants computed one per phase.
//  - LDS: A/B tiles 256x64 bf16, each as 2 halves of 128x64 stored as
//    16 subtiles of 16x32 (1024B) with st_16x32 swizzle (bit5 ^= bit9),
//    double-buffered: 4*16KB (A) + 4*16KB (B) = 128 KiB.
//  - Staging: 1 half-tile/phase via global_load_lds (2 loads/thread),
//    pre-swizzled per-lane GLOBAL source, linear LDS dest (G21).
//  - Publication: wait vmcnt(4) + s_barrier + sched_barrier per phase
//    (counted, never 0 in steady state); phase 3 needs no new half.
// ---------------------------------------------------------------------------
#define WAITBAR(N)                                  \
  do {                                              \
    asm volatile("s_waitcnt vmcnt(" #N ")");        \
    __builtin_amdgcn_s_barrier();                   \
    __builtin_amdgcn_sched_barrier(0);              \
  } while (0)

#define QUAD(D, MH, NH, LOADA)                                                \
  do {                                                                        \
    const int _d = (D);                                                       \
    if (LOADA) {                                                              \
      const int _ab = ((_d * 2 + (MH)) << 14) + (fr << 6) + (fc << 1);        \
      _Pragma("unroll") for (int _i = 0; _i < 4; ++_i)                        \
          _Pragma("unroll") for (int _ks = 0; _ks < 2; ++_ks)                 \
              areg[_i][_ks] = *reinterpret_cast<const short8*>(               \
                  smem + ((_ab + (((wr * 4 + _i) * 2 + _ks) << 10)) ^ aswz)); \
    }                                                                         \
    short8 breg[2][2];                                                        \
    const int _bb =                                                           \
        65536 + ((_d * 2 + (NH)) << 14) + (fr << 6) + (fc << 1);              \
    _Pragma("unroll") for (int _j = 0; _j < 2; ++_j)                          \
        _Pragma("unroll") for (int _ks = 0; _ks < 2; ++_ks)                   \
            breg[_j][_ks] = *reinterpret_cast<const short8*>(                 \
                smem + ((_bb + (((wc * 2 + _j) * 2 + _ks) << 10)) ^ aswz));   \
    __builtin_amdgcn_s_setprio(1);                                            \
    _Pragma("unroll") for (int _i = 0; _i < 4; ++_i)                          \
        _Pragma("unroll") for (int _j = 0; _j < 2; ++_j)                      \
            _Pragma("unroll") for (int _ks = 0; _ks < 2; ++_ks)               \
                acc[MH][NH][_i][_j] =                                         \
                    __builtin_amdgcn_mfma_f32_16x16x32_bf16(                  \
                        areg[_i][_ks], breg[_j][_ks], acc[MH][NH][_i][_j],    \
                        0, 0, 0);                                             \
    __builtin_amdgcn_s_setprio(0);                                            \
  } while (0)

template <int K1, bool CONV1>
__global__ __launch_bounds__(512, 2) void k_conv8ph(
    const __hip_bfloat16* __restrict__ Asrc,   // Hpad (conv1) / Y1all (conv2)
    const __hip_bfloat16* __restrict__ Wt,     // [E][3][N][K1] bf16
    const float* __restrict__ bias,            // [E][N]
    const float* __restrict__ gates,           // conv2 only
    __hip_bfloat16* __restrict__ Yout,         // conv1 only (Y1all)
    float* __restrict__ moe) {                 // conv2 only
  constexpr int NTOT = CONV1 ? kFF : kD;
  constexpr int NX = NTOT / 256;
  constexpr int NY = kM / 256;                 // 32
  constexpr int NWG = kE * NY * NX;
  constexpr int KT1 = K1 / 64;
  constexpr int NT = 3 * KT1;
  extern __shared__ __align__(16) char smem[];

  int lid = blockIdx.x;
  lid = (lid & 7) * (NWG / 8) + (lid >> 3);    // XCD-aware bijective swizzle
  const int e = lid / (NY * NX);
  const int rem = lid - e * (NY * NX);
  const int by = rem / NX, bx = rem - by * NX;
  const int m0 = by * 256, n0 = bx * 256;
  const int b = m0 >> 9, t0 = m0 & (kT - 1);
  const int arow0 = b * kTP + t0;

  const int tid = threadIdx.x;
  const int w = tid >> 6, l = tid & 63;
  const int wr = w >> 2, wc = w & 3;
  const int fr = l & 15, fc = (l >> 4) << 3;
  const int aswz = (fr & 8) ? 32 : 0;
  // staging: lane -> (row-in-subtile, pre-swizzled col byte-group)
  const int srr = l >> 2;
  const int scc = ((l & 3) << 3) ^ ((l & 32) ? 16 : 0);

  const __hip_bfloat16* Apan =
      (CONV1 ? Asrc : (Asrc + (size_t)e * kY1S)) + (size_t)arow0 * K1;
  const __hip_bfloat16* Bpan = Wt + (size_t)e * 3 * kTapStride + (size_t)n0 * K1;

  // stage one half-tile (2 global_load_lds/thread; subtiles s = w, w+8)
  auto stageA = [&](int tau, int d, int mh) {
    const int kk = tau / KT1, kf = (tau % KT1) << 6;
    const __hip_bfloat16* org = Apan + (size_t)(kk + mh * 128) * K1 + kf;
    const int lb = (d * 2 + mh) << 14;
#pragma unroll
    for (int r = 0; r < 2; ++r) {
      const int s = w + r * 8;
      GLOBAL_LOAD_LDS16(org + (size_t)((s >> 1) * 16 + srr) * K1 +
                            ((s & 1) << 5) + scc,
                        smem + lb + (s << 10));
    }
  };
  auto stageB = [&](int tau, int d, int nh) {
    const int kk = tau / KT1, kf = (tau % KT1) << 6;
    const __hip_bfloat16* org =
        Bpan + (size_t)kk * kTapStride + (size_t)(nh * 128) * K1 + kf;
    const int lb = 65536 + ((d * 2 + nh) << 14);
#pragma unroll
    for (int r = 0; r < 2; ++r) {
      const int s = w + r * 8;
      GLOBAL_LOAD_LDS16(org + (size_t)((s >> 1) * 16 + srr) * K1 +
                            ((s & 1) << 5) + scc,
                        smem + lb + (s << 10));
    }
  };

  f32x4 acc[2][2][4][2] = {};
  short8 areg[4][2];

  // prologue: tile 0 -> buf 0, issue order A0,B0,B1,A1
  stageA(0, 0, 0);
  stageB(0, 0, 0);
  stageB(0, 0, 1);
  stageA(0, 0, 1);

  for (int tau = 0; tau < NT - 1; ++tau) {
    const int d = tau & 1, dn = d ^ 1;
    WAITBAR(4); stageA(tau + 1, dn, 0); QUAD(d, 0, 0, true);
    WAITBAR(4); stageB(tau + 1, dn, 0); QUAD(d, 0, 1, false);
    WAITBAR(4); stageB(tau + 1, dn, 1); QUAD(d, 1, 0, true);
                stageA(tau + 1, dn, 1); QUAD(d, 1, 1, false);
  }
  {  // last tile: no staging; drain counts 4 -> 2 -> 0
    const int d = (NT - 1) & 1;
    WAITBAR(4); QUAD(d, 0, 0, true);
    WAITBAR(2); QUAD(d, 0, 1, false);
    WAITBAR(0); QUAD(d, 1, 0, true);
                QUAD(d, 1, 1, false);
  }

  // epilogue
  const int cr = (l >> 4) * 4, cc = l & 15;
  if (CONV1) {
    __hip_bfloat16* Yb = Yout + (size_t)e * kY1S;
    const float* be = bias + (size_t)e * kFF;
    const int orow0 = b * kTP + t0 + 1;
#pragma unroll
    for (int mh = 0; mh < 2; ++mh)
#pragma unroll
      for (int i = 0; i < 4; ++i)
#pragma unroll
        for (int r = 0; r < 4; ++r) {
          const int rl = mh * 128 + wr * 64 + i * 16 + cr + r;
#pragma unroll
          for (int nh = 0; nh < 2; ++nh)
#pragma unroll
            for (int j = 0; j < 2; ++j) {
              const int gc = n0 + nh * 128 + wc * 32 + j * 16 + cc;
              const float v = acc[mh][nh][i][j][r] + be[gc];
              Yb[(size_t)(orow0 + rl) * kFF + gc] =
                  __float2bfloat16(fmaxf(v, 0.f));
            }
        }
  } else {
    const float* be = bias + (size_t)e * kD;
#pragma unroll
    for (int mh = 0; mh < 2; ++mh)
#pragma unroll
      for (int i = 0; i < 4; ++i)
#pragma unroll
        for (int r = 0; r < 4; ++r) {
          const int rl = mh * 128 + wr * 64 + i * 16 + cr + r;
          const int m = m0 + rl;
          const float g = gates[(size_t)m * kE + e];
#pragma unroll
          for (int nh = 0; nh < 2; ++nh)
#pragma unroll
            for (int j = 0; j < 2; ++j) {
              const int gc = n0 + nh * 128 + wc * 32 + j * 16 + cc;
              const float v = acc[mh][nh][i][j][r] + be[gc];
              atomicAdd(&moe[(size_t)m * kD + gc], g * v);
            }
        }
  }
}

// ----- small kernels -----
__global__ __launch_bounds__(256) void k_cnt(const int* __restrict__ mask,
                                             float* __restrict__ cnt) {
  __shared__ float red[256];
  const int i = blockIdx.x * 256 + threadIdx.x;
  float v = (float)mask[i];
  v = block_reduce_sum(v, red);
  if (threadIdx.x == 0) atomicAdd(cnt, v);
}

__global__ __launch_bounds__(256) void k_stats(const float* __restrict__ H,
                                               const int* __restrict__ mask,
                                               float* __restrict__ sums,
                                               float* __restrict__ sumsq) {
  const int ch = blockIdx.x * 256 + threadIdx.x;
  const int r0 = blockIdx.y * 64;
  float s = 0.f, q = 0.f;
  for (int r = r0; r < r0 + 64; ++r) {
    if (mask[r]) {
      const float v = H[(size_t)r * kD + ch];
      s += v;
      q += v * v;
    }
  }
  atomicAdd(&sums[ch], s);
  atomicAdd(&sumsq[ch], q);
}

__global__ __launch_bounds__(256) void k_finalize(
    const float* __restrict__ sums, const float* __restrict__ sumsq,
    const float* __restrict__ cntp, const float* __restrict__ bn_g,
    const float* __restrict__ bn_b, float* __restrict__ aa,
    float* __restrict__ cc) {
  const int d = blockIdx.x * 256 + threadIdx.x;
  const float cnt = fmaxf(*cntp, 1.f);
  const float mean = sums[d] / cnt;
  const float var = sumsq[d] / cnt - mean * mean;
  const float istd = rsqrtf(var + 1e-5f);
  const float a = bn_g[d] * istd;
  aa[d] = a;
  cc[d] = bn_b[d] - mean * a;
}

// masked BN + relu + pe -> Hpad (bf16); gate softmax/top2 -> gates, probs
__global__ __launch_bounds__(256) void k_norm_gate(
    const float* __restrict__ H, const int* __restrict__ mask,
    const float* __restrict__ pe, const float* __restrict__ aa,
    const float* __restrict__ cc, const float* __restrict__ gw,
    __hip_bfloat16* __restrict__ Hpad, float* __restrict__ gates,
    float* __restrict__ probs) {
  __shared__ float red[256];
  __shared__ float glog[4];
  const int r = blockIdx.x;
  const int tid = threadIdx.x;
  const int b = r >> 9;
  const int t = r & (kT - 1);
  const bool mv = mask[r] != 0;
  const size_t orow = (size_t)(b * kTP + t + 1) * kD;
  float gl[4] = {0.f, 0.f, 0.f, 0.f};
#pragma unroll
  for (int j = 0; j < 4; ++j) {
    const int d = tid + j * 256;
    float v = H[(size_t)r * kD + d];
    if (mv) v = v * aa[d] + cc[d];
    v = fmaxf(v, 0.f) + pe[(size_t)t * kD + d];
    Hpad[orow + d] = __float2bfloat16(v);
    const float4 g = *reinterpret_cast<const float4*>(gw + (size_t)d * 4);
    gl[0] += v * g.x; gl[1] += v * g.y; gl[2] += v * g.z; gl[3] += v * g.w;
  }
  for (int e = 0; e < 4; ++e) {
    const float s = block_reduce_sum(gl[e], red);
    if (tid == 0) glog[e] = s;
  }
  __syncthreads();
  if (tid == 0) {
    float lg[4] = {glog[0], glog[1], glog[2], glog[3]};
    const float mx = fmaxf(fmaxf(lg[0], lg[1]), fmaxf(lg[2], lg[3]));
    float ex[4], s = 0.f;
#pragma unroll
    for (int e = 0; e < 4; ++e) { ex[e] = expf(lg[e] - mx); s += ex[e]; }
    int i0 = 0;
    for (int e = 1; e < 4; ++e) if (lg[e] > lg[i0]) i0 = e;
    int i1 = -1;
    for (int e = 0; e < 4; ++e) {
      if (e == i0) continue;
      if (i1 < 0 || lg[e] > lg[i1]) i1 = e;
    }
    const float g0 = 1.f / (1.f + expf(lg[i1] - lg[i0]));
    float gv[4] = {0.f, 0.f, 0.f, 0.f};
    gv[i0] = g0;
    gv[i1] = 1.f - g0;
    *reinterpret_cast<float4*>(gates + (size_t)r * 4) =
        make_float4(gv[0], gv[1], gv[2], gv[3]);
    const float inv_s = 1.f / s;
    *reinterpret_cast<float4*>(probs + (size_t)r * 4) =
        make_float4(ex[0] * inv_s, ex[1] * inv_s, ex[2] * inv_s, ex[3] * inv_s);
  }
}

__global__ __launch_bounds__(256) void k_ln(
    const float* __restrict__ moe, const float* __restrict__ g,
    const float* __restrict__ b, float* __restrict__ feat,
    float* __restrict__ featn, __hip_bfloat16* __restrict__ featb) {
  __shared__ float red[256];
  const int r = blockIdx.x;
  const int tid = threadIdx.x;
  float v[4];
  float s = 0.f, q = 0.f;
#pragma unroll
  for (int j = 0; j < 4; ++j) {
    v[j] = moe[(size_t)r * kD + tid + j * 256];
    s += v[j];
    q += v[j] * v[j];
  }
  const float sum = block_reduce_sum(s, red);
  const float mu = sum * (1.f / kD);
  const float sq = block_reduce_sum(q, red);
  const float var = sq * (1.f / kD) - mu * mu;
  const float istd = rsqrtf(var + 1e-6f);
  float f[4];
  float fs = 0.f;
#pragma unroll
  for (int j = 0; j < 4; ++j) {
    const int d = tid + j * 256;
    f[j] = (v[j] - mu) * istd * g[d] + b[d];
    feat[(size_t)r * kD + d] = f[j];
    featb[(size_t)r * kD + d] = __float2bfloat16(f[j]);
    fs += f[j] * f[j];
  }
  const float nrm2 = block_reduce_sum(fs, red);
  const float scale = 1.f / fmaxf(sqrtf(nrm2), 1e-12f);
#pragma unroll
  for (int j = 0; j < 4; ++j) {
    const int d = tid + j * 256;
    featn[(size_t)r * kD + d] = f[j] * scale;
  }
}

__global__ __launch_bounds__(256) void k_softmax(
    const float* __restrict__ logits, float* __restrict__ logp,
    float* __restrict__ p) {
  __shared__ float red[256];
  const int r = blockIdx.x;
  const int tid = threadIdx.x;
  float lv[5];
  float mx = -1e30f;
#pragma unroll
  for (int j = 0; j < 5; ++j) {
    const int c = tid + j * 256;
    if (c < kCLS) {
      lv[j] = logits[(size_t)r * kCLS + c];
      mx = fmaxf(mx, lv[j]);
    }
  }
  mx = block_reduce_max(mx, red);
  float s = 0.f;
#pragma unroll
  for (int j = 0; j < 5; ++j) {
    const int c = tid + j * 256;
    if (c < kCLS) s += expf(lv[j] - mx);
  }
  s = block_reduce_sum(s, red);
  const float lse = mx + logf(s);
#pragma unroll
  for (int j = 0; j < 5; ++j) {
    const int c = tid + j * 256;
    if (c < kCLS) {
      const float lp = lv[j] - lse;
      logp[(size_t)r * kCLS + c] = lp;
      p[(size_t)r * kCLS + c] = expf(lp);
    }
  }
}

// aux = E * sum_e (frac_e * imp_e); single block, no global atomics
__global__ __launch_bounds__(256) void k_aux(const float* __restrict__ probs,
                                             const float* __restrict__ gates,
                                             float* __restrict__ out) {
  __shared__ float red[256];
  const int tid = threadIdx.x;
  float si[4] = {0.f, 0.f, 0.f, 0.f};
  float sf[4] = {0.f, 0.f, 0.f, 0.f};
  for (int i = tid; i < kM; i += 256) {
    const float4 p = *reinterpret_cast<const float4*>(probs + (size_t)i * 4);
    const float4 g = *reinterpret_cast<const float4*>(gates + (size_t)i * 4);
    si[0] += p.x; si[1] += p.y; si[2] += p.z; si[3] += p.w;
    sf[0] += (g.x > 0.f) ? 1.f : 0.f;
    sf[1] += (g.y > 0.f) ? 1.f : 0.f;
    sf[2] += (g.z > 0.f) ? 1.f : 0.f;
    sf[3] += (g.w > 0.f) ? 1.f : 0.f;
  }
  float tot = 0.f;
  for (int e = 0; e < 4; ++e) {
    const float S = block_reduce_sum(si[e], red);
    const float F = block_reduce_sum(sf[e], red);
    tot += (F / (float)kM) * (S / (float)kM);
  }
  if (tid == 0) out[0] = (float)kE * tot;
}

}  // namespace

extern "C" void kernel_launch(void* const* d_in, const int* in_sizes, int n_in,
                              void* d_out, int out_size, void* d_ws,
                              size_t ws_size, hipStream_t stream) {
  const float* x     = (const float*)d_in[0];
  const int*   mask  = (const int*)d_in[1];
  const float* fc1_w = (const float*)d_in[2];
  const float* fc1_b = (const float*)d_in[3];
  const float* bn_g  = (const float*)d_in[4];
  const float* bn_b  = (const float*)d_in[5];
  const float* pe    = (const float*)d_in[6];
  const float* gw    = (const float*)d_in[7];
  const float* ew1   = (const float*)d_in[8];
  const float* eb1   = (const float*)d_in[9];
  const float* ew2   = (const float*)d_in[10];
  const float* eb2   = (const float*)d_in[11];
  const float* ln_g  = (const float*)d_in[12];
  const float* ln_b  = (const float*)d_in[13];
  const float* out_w = (const float*)d_in[14];
  const float* out_b = (const float*)d_in[15];

  float* ws = (float*)d_ws;

  float* outf   = (float*)d_out;
  float* feat   = outf;
  float* featn  = outf + kBTD;
  float* logits = outf + 2 * kBTD;
  float* logp   = logits + kBTC;
  float* pprob  = logp + kBTC;
  float* aux    = pprob + kBTC;

  const bool batched = ws_size >= BW_END * sizeof(float);

  if (batched) {
    float* H     = ws + BW_H;                       // fc1 out; later MOE
    __hip_bfloat16* HPAD  = (__hip_bfloat16*)(ws + BW_HPAD);
    __hip_bfloat16* Y1ALL = (__hip_bfloat16*)(ws + BW_Y1);
    __hip_bfloat16* XHI   = Y1ALL;                  // fc1 phase
    __hip_bfloat16* XLO   = XHI + kBTD;             // fc1 phase
    __hip_bfloat16* FEATB = Y1ALL;                  // epilogue
    __hip_bfloat16* W1T   = (__hip_bfloat16*)(ws + BW_W1T);
    __hip_bfloat16* W2T   = (__hip_bfloat16*)(ws + BW_W2T);
    float* GATES = ws + BW_GATES;
    float* PROBS = ws + BW_PROBS;
    __hip_bfloat16* W1HI = (__hip_bfloat16*)(ws + BW_W1HI);
    __hip_bfloat16* W1LO = (__hip_bfloat16*)(ws + BW_W1LO);
    __hip_bfloat16* OWB  = (__hip_bfloat16*)(ws + BW_OWB);
    float* SUMS  = ws + BW_SUMS;
    float* MOE   = H;

    k_zero<<<dim3((WS_ZERON + 255) / 256), 256, 0, stream>>>(SUMS, WS_ZERON);
    k_split<<<dim3((int)(kBTD / 4 + 255) / 256), 256, 0, stream>>>(
        x, XHI, XLO, (int)(kBTD / 4));
    k_split<<<dim3((kD * kD / 4 + 255) / 256), 256, 0, stream>>>(
        fc1_w, W1HI, W1LO, kD * kD / 4);
    k_fc1_mfma<<<dim3(kD / 128, kM / 128), 256, 0, stream>>>(
        XHI, XLO, W1HI, W1LO, fc1_b, H);
    k_zero_bnd_all<<<dim3(2 * kB * (1 + kE)), 256, 0, stream>>>(HPAD, Y1ALL);
    k_wt_all<<<dim3((int)(((size_t)kE * kFF * kD + 255) / 256)), 256, 0,
               stream>>>(ew1, ew2, W1T, W2T);
    k_cnt<<<dim3(kM / 256), 256, 0, stream>>>(mask, ws + BW_CNT);
    k_stats<<<dim3(kD / 256, kM / 64), 256, 0, stream>>>(H, mask, SUMS,
                                                         ws + BW_SUMSQ);
    k_finalize<<<dim3(kD / 256), 256, 0, stream>>>(
        SUMS, ws + BW_SUMSQ, ws + BW_CNT, bn_g, bn_b, ws + BW_AA, ws + BW_CC);
    k_norm_gate<<<dim3(kM), 256, 0, stream>>>(H, mask, pe, ws + BW_AA,
                                              ws + BW_CC, gw, HPAD, GATES,
                                              PROBS);
    // H is dead now; zero MOE (alias of H) for atomic accumulation
    k_zero<<<dim3((int)((kBTD + 255) / 256)), 256, 0, stream>>>(MOE,
                                                                (int)kBTD);
    // 8-phase 256^2 convs: 1024 / 512 blocks, 512 threads, 128 KiB LDS
    k_conv8ph<kD, true><<<dim3(kE * (kM / 256) * (kFF / 256)), 512, 131072,
                          stream>>>(HPAD, W1T, eb1, nullptr, Y1ALL, nullptr);
    k_conv8ph<kFF, false><<<dim3(kE * (kM / 256) * (kD / 256)), 512, 131072,
                            stream>>>(Y1ALL, W2T, eb2, GATES, nullptr, MOE);
    k_ln<<<dim3(kM), 256, 0, stream>>>(MOE, ln_g, ln_b, feat, featn, FEATB);
    k_wcast_pad<<<dim3((int)((size_t)kCLSP * kD + 255) / 256), 256, 0,
                  stream>>>(out_w, OWB);
    k_cls_mfma<<<dim3(kCLSP / 128, kM / 128), 256, 0, stream>>>(FEATB, OWB,
                                                                out_b, logits);
    k_softmax<<<dim3(kM), 256, 0, stream>>>(logits, logp, pprob);
    k_aux<<<1, 256, 0, stream>>>(PROBS, GATES, aux);
    return;
  }

  // ---------------- fallback: previous verified serial path ----------------
  float* H     = ws + WS_H;
  __hip_bfloat16* HPAD  = (__hip_bfloat16*)(ws + WS_HPAD);
  __hip_bfloat16* Y1PAD = (__hip_bfloat16*)(ws + WS_Y1P);
  __hip_bfloat16* XHI   = (__hip_bfloat16*)(ws + WS_Y1P);
  __hip_bfloat16* XLO   = XHI + kBTD;
  __hip_bfloat16* FEATB = (__hip_bfloat16*)(ws + WS_Y1P);
  __hip_bfloat16* W1T   = (__hip_bfloat16*)(ws + WS_W1T);
  __hip_bfloat16* W2T   = (__hip_bfloat16*)(ws + WS_W2T);
  float* GATES = ws + WS_GATES;
  float* PROBS = ws + WS_PROBS;
  __hip_bfloat16* W1HI = (__hip_bfloat16*)(ws + WS_W1HI);
  __hip_bfloat16* W1LO = (__hip_bfloat16*)(ws + WS_W1LO);
  __hip_bfloat16* OWB  = (__hip_bfloat16*)(ws + WS_OWB);
  float* SUMS  = ws + WS_SUMS;
  float* SUMSQ = ws + WS_SUMSQ;
  float* CNT   = ws + WS_CNT;
  float* AA    = ws + WS_AA;
  float* CC    = ws + WS_CC;
  float* MOE   = H;

  k_zero<<<dim3((WS_ZERON + 255) / 256), 256, 0, stream>>>(SUMS, WS_ZERON);
  k_split<<<dim3((int)(kBTD / 4 + 255) / 256), 256, 0, stream>>>(x, XHI, XLO,
                                                                 (int)(kBTD / 4));
  k_split<<<dim3((kD * kD / 4 + 255) / 256), 256, 0, stream>>>(
      fc1_w, W1HI, W1LO, kD * kD / 4);
  k_fc1_mfma<<<dim3(kD / 128, kM / 128), 256, 0, stream>>>(XHI, XLO, W1HI,
                                                           W1LO, fc1_b, H);
  k_zero_bnd<<<dim3(2 * kB), 256, 0, stream>>>(HPAD, Y1PAD);
  k_cnt<<<dim3(kM / 256), 256, 0, stream>>>(mask, CNT);
  k_stats<<<dim3(kD / 256, kM / 64), 256, 0, stream>>>(H, mask, SUMS, SUMSQ);
  k_finalize<<<dim3(kD / 256), 256, 0, stream>>>(SUMS, SUMSQ, CNT, bn_g, bn_b,
                                                 AA, CC);
  k_norm_gate<<<dim3(kM), 256, 0, stream>>>(H, mask, pe, AA, CC, gw, HPAD,
                                            GATES, PROBS);
  for (int e = 0; e < kE; ++e) {
    k_wt<<<dim3((kFF * kD + 255) / 256), 256, 0, stream>>>(
        ew1 + (size_t)e * kFF * kD * 3, W1T, kFF * kD);
    k_wt<<<dim3((kD * kFF + 255) / 256), 256, 0, stream>>>(
        ew2 + (size_t)e * kD * kFF * 3, W2T, kD * kFF);
    k_conv1_mfma<<<dim3(kFF / 128, kM / 128), 256, 0, stream>>>(
        HPAD, W1T, eb1 + (size_t)e * kFF, Y1PAD);
    k_conv2_mfma<<<dim3(kD / 128, kM / 128), 256, 0, stream>>>(
        Y1PAD, W2T, eb2 + (size_t)e * kD, GATES, e, MOE);
  }
  k_ln<<<dim3(kM), 256, 0, stream>>>(MOE, ln_g, ln_b, feat, featn, FEATB);
  k_wcast_pad<<<dim3((int)((size_t)kCLSP * kD + 255) / 256), 256, 0, stream>>>(
      out_w, OWB);
  k_cls_mfma<<<dim3(kCLSP / 128, kM / 128), 256, 0, stream>>>(FEATB, OWB,
                                                              out_b, logits);
  k_softmax<<<dim3(kM), 256, 0, stream>>>(logits, logp, pprob);
  k_aux<<<1, 256, 0, stream>>>(PROBS, GATES, aux);
}